// Round 11
// baseline (28.927 us; speedup 1.0000x reference)
//
#include <hip/hip_runtime.h>

#define NQ 11

// Two samples per wave (A and B), each a 2048-amplitude real statevector in
// 16 float2 VGPRs.  Amplitude index i (wire w <-> bit (10-w) of i):
//   i = (k<<7) | (comp<<6) | lane
//   wires 0..3  -> k bits 3..0    (packed float2 register butterflies)
//   wire  4     -> comp           (within-float2 butterfly)
//   wires 5..10 -> lane bits 5..0 (cross-lane butterflies)
// CZ gates folded into the NEXT RY's coefficients (verified r3/r5/r6/r8).
// Cross-lane: mask 32/16 -> __shfl_xor BATCHED; masks 8,4,2,1 -> DPP.
// Two independent per-sample dataflow chains give ILP=2 to hide DS/DPP and
// FMA latency at 1 wave/SIMD (1024 waves; stalls decorrelated by construction).
//
// ROUND 10 DELTA vs r8 (which passed but spilled at VGPR=76):
//   amdgpu_waves_per_eu(1,2) caps the allocator's assumed occupancy at
//   2 waves/EU -> up to 256 VGPRs/wave, so the ~180 live registers fit
//   without scratch spill. This is the ONLY change.

typedef float f32x2 __attribute__((ext_vector_type(2)));

__device__ __forceinline__ f32x2 b2(float s) { f32x2 r; r.x = s; r.y = s; return r; }
__device__ __forceinline__ f32x2 fma2(f32x2 a, f32x2 b, f32x2 c) {
    return __builtin_elementwise_fma(a, b, c);
}

template <int CTRL>
__device__ __forceinline__ float dpp_mov(float x) {
    const int xi = __builtin_bit_cast(int, x);
    return __builtin_bit_cast(float,
        __builtin_amdgcn_update_dpp(xi, xi, CTRL, 0xf, 0xf, false));
}
#define DPP_XOR1 0xB1   // quad_perm [1,0,3,2]
#define DPP_XOR2 0x4E   // quad_perm [2,3,0,1]
#define DPP_XOR3 0x1B   // quad_perm [3,2,1,0]
#define DPP_XOR7 0x141  // row_half_mirror
#define DPP_XOR8 0x128  // row_ror:8 (xor-8 within 16-lane row)

// Packed register butterfly on k-bit KB for BOTH states; preceding CZ sign:
// -1 iff (k0 & KSB).
#define RY_K_F2(KB, KSB, C, S)                                               \
    {                                                                        \
        const f32x2 Cv = b2(C), Sv = b2(S);                                  \
        _Pragma("unroll")                                                    \
        for (int g = 0; g < 8; ++g) {                                        \
            const int k0 = ((g >> (KB)) << ((KB) + 1)) | (g & ((1 << (KB)) - 1)); \
            const int k1 = k0 | (1 << (KB));                                 \
            const f32x2 aA = vA[k0], bA = vA[k1];                            \
            const f32x2 aB = vB[k0], bB = vB[k1];                            \
            if (k0 & (KSB)) {                                                \
                vA[k0] = fma2(Cv, aA, Sv * bA);                              \
                vA[k1] = fma2(Sv, aA, -(Cv * bA));                           \
                vB[k0] = fma2(Cv, aB, Sv * bB);                              \
                vB[k1] = fma2(Sv, aB, -(Cv * bB));                           \
            } else {                                                         \
                vA[k0] = fma2(Cv, aA, -(Sv * bA));                           \
                vA[k1] = fma2(Sv, aA, Cv * bA);                              \
                vB[k0] = fma2(Cv, aB, -(Sv * bB));                           \
                vB[k1] = fma2(Sv, aB, Cv * bB);                              \
            }                                                                \
        }                                                                    \
    }

// DS shuffle gate, BATCHED: all 64 partner fetches (2 samples x 32 words)
// issued before any use -> single waitcnt drain, latency amortized.
#define RY_DS2(SHFL, CV, SV)                                                 \
    {                                                                        \
        f32x2 pA[16], pB[16];                                                \
        _Pragma("unroll")                                                    \
        for (int k = 0; k < 16; ++k) {                                       \
            pA[k].x = SHFL(vA[k].x); pA[k].y = SHFL(vA[k].y);                \
            pB[k].x = SHFL(vB[k].x); pB[k].y = SHFL(vB[k].y);                \
        }                                                                    \
        _Pragma("unroll")                                                    \
        for (int k = 0; k < 16; ++k) {                                       \
            vA[k] = fma2(CV, vA[k], (SV) * pA[k]);                           \
            vB[k] = fma2(CV, vB[k], (SV) * pB[k]);                           \
        }                                                                    \
    }

// DPP lane gate for both states (VALU pipe, short latency).
#define RY_DPP2(PGETX, CV, SV)                                               \
    _Pragma("unroll")                                                        \
    for (int k = 0; k < 16; ++k) {                                           \
        f32x2 pa, pb;                                                        \
        pa.x = PGETX(vA[k].x); pa.y = PGETX(vA[k].y);                        \
        pb.x = PGETX(vB[k].x); pb.y = PGETX(vB[k].y);                        \
        vA[k] = fma2(CV, vA[k], (SV) * pa);                                  \
        vB[k] = fma2(CV, vB[k], (SV) * pb);                                  \
    }

__global__ void __launch_bounds__(256)
__attribute__((amdgpu_waves_per_eu(1, 2)))
qru_kernel(
    const float* __restrict__ x,   // [2048, 16]
    const float* __restrict__ w,   // [11]
    float* __restrict__ out)       // [2048, 11]
{
    const int lane = threadIdx.x & 63;
    const int g    = blockIdx.x * 4 + (threadIdx.x >> 6);  // wave id 0..1023
    const int nA   = 2 * g, nB = 2 * g + 1;

    // ---- input angles (vectorized) + half-angle sin/cos, both samples ----
    const float4 a0 = *(const float4*)(x + nA * 16);
    const float4 a1 = *(const float4*)(x + nA * 16 + 4);
    const float4 a2 = *(const float4*)(x + nA * 16 + 8);
    const float4 b0 = *(const float4*)(x + nB * 16);
    const float4 b1 = *(const float4*)(x + nB * 16 + 4);
    const float4 b2_ = *(const float4*)(x + nB * 16 + 8);
    const float xvA[NQ] = {a0.x, a0.y, a0.z, a0.w, a1.x, a1.y, a1.z, a1.w,
                           a2.x, a2.y, a2.z};
    const float xvB[NQ] = {b0.x, b0.y, b0.z, b0.w, b1.x, b1.y, b1.z, b1.w,
                           b2_.x, b2_.y, b2_.z};
    float ciA[NQ], siA[NQ], ciB[NQ], siB[NQ];
#pragma unroll
    for (int q = 0; q < NQ; ++q) {
        const float hA = xvA[q] * 0.5f, hB = xvB[q] * 0.5f;
        siA[q] = __sinf(hA); ciA[q] = __cosf(hA);
        siB[q] = __sinf(hB); ciB[q] = __cosf(hB);
    }
    float cw[NQ], sw[NQ];
#pragma unroll
    for (int q = 0; q < NQ; ++q) {
        const float h = w[q] * 0.5f;
        sw[q] = __sinf(h); cw[q] = __cosf(h);
    }

    // ---- initial product states ----
    const float laneFA =
        ((lane & 32) ? siA[5]  : ciA[5])  *
        ((lane & 16) ? siA[6]  : ciA[6])  *
        ((lane & 8)  ? siA[7]  : ciA[7])  *
        ((lane & 4)  ? siA[8]  : ciA[8])  *
        ((lane & 2)  ? siA[9]  : ciA[9])  *
        ((lane & 1)  ? siA[10] : ciA[10]);
    const float laneFB =
        ((lane & 32) ? siB[5]  : ciB[5])  *
        ((lane & 16) ? siB[6]  : ciB[6])  *
        ((lane & 8)  ? siB[7]  : ciB[7])  *
        ((lane & 4)  ? siB[8]  : ciB[8])  *
        ((lane & 2)  ? siB[9]  : ciB[9])  *
        ((lane & 1)  ? siB[10] : ciB[10]);

    f32x2 vA[16], vB[16];
#pragma unroll
    for (int k = 0; k < 16; ++k) {
        const float bA = laneFA * ((k & 8) ? siA[0] : ciA[0])
                                * ((k & 4) ? siA[1] : ciA[1])
                                * ((k & 2) ? siA[2] : ciA[2])
                                * ((k & 1) ? siA[3] : ciA[3]);
        vA[k].x = bA * ciA[4];
        vA[k].y = bA * siA[4];
        const float bB = laneFB * ((k & 8) ? siB[0] : ciB[0])
                                * ((k & 4) ? siB[1] : ciB[1])
                                * ((k & 2) ? siB[2] : ciB[2])
                                * ((k & 1) ? siB[3] : ciB[3]);
        vB[k].x = bB * ciB[4];
        vB[k].y = bB * siB[4];
    }

    // ---- folded per-lane coefficient constants (verified r3/r5/r6),
    //      all sample-independent (lane + weights only) ----
    const float X0m = (lane & 1) ?  sw[0] : -sw[0];
    const float Y0m = (lane & 1) ? -cw[0] :  cw[0];
    const float SS5 = (lane & 32) ?  sw[5] : -sw[5];
    const float C5m = (lane & 32) ? -cw[5] :  cw[5];
    f32x2 Cv5; Cv5.x = cw[5]; Cv5.y = C5m;
    f32x2 Sv5; Sv5.x = SS5;   Sv5.y = sw[5];
    const f32x2 C6v  = b2(((lane & 48) == 48) ? -cw[6]  : cw[6]);
    const f32x2 S6v  = b2((lane & 48) ? sw[6]  : -sw[6]);
    const f32x2 C7v  = b2(((lane & 24) == 24) ? -cw[7]  : cw[7]);
    const f32x2 S7v  = b2((lane & 24) ? sw[7]  : -sw[7]);
    const f32x2 C8v  = b2(((lane & 12) == 12) ? -cw[8]  : cw[8]);
    const f32x2 S8v  = b2((lane & 12) ? sw[8]  : -sw[8]);
    const f32x2 C9v  = b2(((lane & 6)  == 6)  ? -cw[9]  : cw[9]);
    const f32x2 S9v  = b2((lane & 6)  ? sw[9]  : -sw[9]);
    const f32x2 C10v = b2(((lane & 3)  == 3)  ? -cw[10] : cw[10]);
    const f32x2 S10v = b2((lane & 3)  ? sw[10] : -sw[10]);

    // RY4 (comp butterfly), incoming CZ(3,4): sigma1 = -1 iff k odd.
    f32x2 C4p; C4p.x = cw[4];  C4p.y =  cw[4];
    f32x2 S4p; S4p.x = -sw[4]; S4p.y =  sw[4];
    f32x2 C4m; C4m.x = cw[4];  C4m.y = -cw[4];
    f32x2 S4m; S4m.x = sw[4];  S4m.y =  sw[4];

    auto shfl32 = [](float t) { return __shfl_xor(t, 32); };
    auto shfl16 = [](float t) { return __shfl_xor(t, 16); };
    auto dppx8  = [](float t) { return dpp_mov<DPP_XOR8>(t); };
    auto dppx4  = [](float t) { return dpp_mov<DPP_XOR3>(dpp_mov<DPP_XOR7>(t)); };
    auto dppx2  = [](float t) { return dpp_mov<DPP_XOR2>(t); };
    auto dppx1  = [](float t) { return dpp_mov<DPP_XOR1>(t); };

    auto layer = [&](float X0, float Y0) {
        // RY0 on k bit 3 (incoming CZ folded into X0/Y0), both samples
        {
            const f32x2 c0 = b2(cw[0]), s0 = b2(sw[0]);
            const f32x2 x0 = b2(X0),    y0 = b2(Y0);
#pragma unroll
            for (int k = 0; k < 8; ++k) {
                const f32x2 aA = vA[k], bA = vA[k | 8];
                vA[k]     = fma2(c0, aA, x0 * bA);
                vA[k | 8] = fma2(s0, aA, y0 * bA);
                const f32x2 aB = vB[k], bB = vB[k | 8];
                vB[k]     = fma2(c0, aB, x0 * bB);
                vB[k | 8] = fma2(s0, aB, y0 * bB);
            }
        }
        RY_K_F2(2, 8, cw[1], sw[1])     // RY1, fold CZ(0,1)
        RY_K_F2(1, 4, cw[2], sw[2])     // RY2, fold CZ(1,2)
        RY_K_F2(0, 2, cw[3], sw[3])     // RY3, fold CZ(2,3)

        // RY4 (component), fold CZ(3,4) (k bit0), both samples
#pragma unroll
        for (int k = 0; k < 16; ++k) {
            const f32x2 sA = __builtin_shufflevector(vA[k], vA[k], 1, 0);
            const f32x2 sB = __builtin_shufflevector(vB[k], vB[k], 1, 0);
            vA[k] = (k & 1) ? fma2(C4m, vA[k], S4m * sA)
                            : fma2(C4p, vA[k], S4p * sA);
            vB[k] = (k & 1) ? fma2(C4m, vB[k], S4m * sB)
                            : fma2(C4p, vB[k], S4p * sB);
        }

        RY_DS2(shfl32, Cv5, Sv5)        // RY5,  fold CZ(4,5)  — DS batched
        RY_DS2(shfl16, C6v, S6v)        // RY6,  fold CZ(5,6)  — DS batched
        RY_DPP2(dppx8, C7v,  S7v)       // RY7,  fold CZ(6,7)  — DPP
        RY_DPP2(dppx4, C8v,  S8v)       // RY8,  fold CZ(7,8)  — DPP x2
        RY_DPP2(dppx2, C9v,  S9v)       // RY9,  fold CZ(8,9)  — DPP
        RY_DPP2(dppx1, C10v, S10v)      // RY10, fold CZ(9,10) — DPP
        // CZ(10,0) -> folded into next layer's RY0; pure sign after last.
    };

    layer(-sw[0], cw[0]);               // layer 0: RY0 has no incoming CZ
#pragma unroll 1
    for (int l = 1; l < 6; ++l) layer(X0m, Y0m);

    // ---- measurement: out[w] = sum_i amp_i^2 * (1 - 2*bit_w(i)) ----
    f32x2 TA = b2(0.f), A3 = b2(0.f), A2 = b2(0.f), A1 = b2(0.f), A0 = b2(0.f);
    f32x2 TB = b2(0.f), B3 = b2(0.f), B2 = b2(0.f), B1 = b2(0.f), B0 = b2(0.f);
#pragma unroll
    for (int k = 0; k < 16; ++k) {
        const f32x2 pA = vA[k] * vA[k];
        const f32x2 pB = vB[k] * vB[k];
        TA = TA + pA;  TB = TB + pB;
        if (k & 8) { A3 = A3 + pA; B3 = B3 + pB; }
        if (k & 4) { A2 = A2 + pA; B2 = B2 + pB; }
        if (k & 2) { A1 = A1 + pA; B1 = B1 + pB; }
        if (k & 1) { A0 = A0 + pA; B0 = B0 + pB; }
    }
    const float totA = TA.x + TA.y, totB = TB.x + TB.y;

    float qA[NQ], qB[NQ];
    qA[0] = totA - 2.f * (A3.x + A3.y);  qB[0] = totB - 2.f * (B3.x + B3.y);
    qA[1] = totA - 2.f * (A2.x + A2.y);  qB[1] = totB - 2.f * (B2.x + B2.y);
    qA[2] = totA - 2.f * (A1.x + A1.y);  qB[2] = totB - 2.f * (B1.x + B1.y);
    qA[3] = totA - 2.f * (A0.x + A0.y);  qB[3] = totB - 2.f * (B0.x + B0.y);
    qA[4] = totA - 2.f * TA.y;           qB[4] = totB - 2.f * TB.y;
    qA[5]  = (lane & 32) ? -totA : totA; qB[5]  = (lane & 32) ? -totB : totB;
    qA[6]  = (lane & 16) ? -totA : totA; qB[6]  = (lane & 16) ? -totB : totB;
    qA[7]  = (lane & 8)  ? -totA : totA; qB[7]  = (lane & 8)  ? -totB : totB;
    qA[8]  = (lane & 4)  ? -totA : totA; qB[8]  = (lane & 4)  ? -totB : totB;
    qA[9]  = (lane & 2)  ? -totA : totA; qB[9]  = (lane & 2)  ? -totB : totB;
    qA[10] = (lane & 1)  ? -totA : totA; qB[10] = (lane & 1)  ? -totB : totB;

    // stage-major wave reduction: 22 independent DS ops per DS stage
#pragma unroll
    for (int wq = 0; wq < NQ; ++wq) { qA[wq] += __shfl_xor(qA[wq], 32);
                                      qB[wq] += __shfl_xor(qB[wq], 32); }
#pragma unroll
    for (int wq = 0; wq < NQ; ++wq) { qA[wq] += __shfl_xor(qA[wq], 16);
                                      qB[wq] += __shfl_xor(qB[wq], 16); }
#pragma unroll
    for (int wq = 0; wq < NQ; ++wq) { qA[wq] += dpp_mov<DPP_XOR8>(qA[wq]);
                                      qB[wq] += dpp_mov<DPP_XOR8>(qB[wq]); }
#pragma unroll
    for (int wq = 0; wq < NQ; ++wq) {
        qA[wq] += dpp_mov<DPP_XOR3>(dpp_mov<DPP_XOR7>(qA[wq]));
        qB[wq] += dpp_mov<DPP_XOR3>(dpp_mov<DPP_XOR7>(qB[wq]));
    }
#pragma unroll
    for (int wq = 0; wq < NQ; ++wq) { qA[wq] += dpp_mov<DPP_XOR2>(qA[wq]);
                                      qB[wq] += dpp_mov<DPP_XOR2>(qB[wq]); }
#pragma unroll
    for (int wq = 0; wq < NQ; ++wq) { qA[wq] += dpp_mov<DPP_XOR1>(qA[wq]);
                                      qB[wq] += dpp_mov<DPP_XOR1>(qB[wq]); }

    if (lane == 0) {
#pragma unroll
        for (int wq = 0; wq < NQ; ++wq) {
            out[nA * NQ + wq] = qA[wq];
            out[nB * NQ + wq] = qB[wq];
        }
    }
}

extern "C" void kernel_launch(void* const* d_in, const int* in_sizes, int n_in,
                              void* d_out, int out_size, void* d_ws, size_t ws_size,
                              hipStream_t stream) {
    const float* x = (const float*)d_in[0];   // [8,256,16] f32
    const float* w = (const float*)d_in[1];   // [11] f32
    float* out = (float*)d_out;               // [8,256,11] f32

    // 2048 samples, 2 per wave, 4 waves per block -> 256 blocks (1 block/CU)
    qru_kernel<<<256, 256, 0, stream>>>(x, w, out);
}

// Round 13
// 25.713 us; speedup vs baseline: 1.1250x; 1.1250x over previous
//
#include <hip/hip_runtime.h>

#define NQ 11

// One wave per sample; 2048-amplitude real statevector in 16 float2 VGPR
// pairs per lane.  Amplitude index i (wire w <-> bit (10-w) of i):
//   i = (k<<7) | (comp<<6) | lane
//   wires 0..3  -> k bits 3..0    (packed float2 register butterflies)
//   wire  4     -> comp           (within-float2 butterfly)
//   wires 5..10 -> lane bits 5..0 (cross-lane butterflies)
// CZ gates folded into the NEXT RY's coefficients (verified r3/r5/r6/r9).
//
// Cross-lane mask 32/16: v_permlane{32,16}_swap_b32 via INLINE ASM, with the
// swap's OUTPUT ORDER determined by an inline-asm runtime probe (r12 evidence:
// asm permlane gives bounded/unitary-wrong output == pure output-order
// misinterpretation; builtin gives unbounded blow-up == compiler-model vs HW
// inconsistency under folding). Mode map:
//   both-direct (r12's config, empirically falsified) -> shfl fallback
//   any-reversed combos -> templated permlane path matching probed HW order
//   unrecognized lane map -> shfl fallback (r9 parity, no regression)
// Masks 8,4,2,1 -> DPP (verified r5/r6/r9).

typedef float f32x2 __attribute__((ext_vector_type(2)));

template <int N> struct IC { static constexpr int value = N; };

__device__ __forceinline__ f32x2 b2(float s) { f32x2 r; r.x = s; r.y = s; return r; }
__device__ __forceinline__ f32x2 fma2(f32x2 a, f32x2 b, f32x2 c) {
    return __builtin_elementwise_fma(a, b, c);
}

__device__ __forceinline__ void pswap32(float& a, float& b) {
    asm volatile("v_permlane32_swap_b32 %0, %1" : "+v"(a), "+v"(b));
}
__device__ __forceinline__ void pswap16(float& a, float& b) {
    asm volatile("v_permlane16_swap_b32 %0, %1" : "+v"(a), "+v"(b));
}
__device__ __forceinline__ void pswap32u(unsigned& a, unsigned& b) {
    asm volatile("v_permlane32_swap_b32 %0, %1" : "+v"(a), "+v"(b));
}
__device__ __forceinline__ void pswap16u(unsigned& a, unsigned& b) {
    asm volatile("v_permlane16_swap_b32 %0, %1" : "+v"(a), "+v"(b));
}

template <int CTRL>
__device__ __forceinline__ float dpp_mov(float x) {
    const int xi = __builtin_bit_cast(int, x);
    return __builtin_bit_cast(float,
        __builtin_amdgcn_update_dpp(xi, xi, CTRL, 0xf, 0xf, false));
}
#define DPP_XOR1 0xB1   // quad_perm [1,0,3,2]
#define DPP_XOR2 0x4E   // quad_perm [2,3,0,1]
#define DPP_XOR3 0x1B   // quad_perm [3,2,1,0]
#define DPP_XOR7 0x141  // row_half_mirror
#define DPP_XOR8 0x128  // row_ror:8 (xor-8 within 16-lane row)

// Packed butterfly on k-bit KB; preceding CZ sign: -1 iff (k0 & KSB).
#define RY_K_F(KB, KSB, C, S)                                                \
    _Pragma("unroll")                                                        \
    for (int g = 0; g < 8; ++g) {                                            \
        const int k0 = ((g >> (KB)) << ((KB) + 1)) | (g & ((1 << (KB)) - 1));\
        const int k1 = k0 | (1 << (KB));                                     \
        const f32x2 a_ = v2[k0], b_ = v2[k1];                                \
        const f32x2 Cv = b2(C), Sv = b2(S);                                  \
        if (k0 & (KSB)) {                                                    \
            v2[k0] = fma2(Cv, a_, Sv * b_);                                  \
            v2[k1] = fma2(Sv, a_, -(Cv * b_));                               \
        } else {                                                             \
            v2[k0] = fma2(Cv, a_, -(Sv * b_));                               \
            v2[k1] = fma2(Sv, a_, Cv * b_);                                  \
        }                                                                    \
    }

// DS shuffle gate, BATCHED (verified r9 fallback path).
#define RY_DS_B(SHFL, CV, SV)                                                \
    {                                                                        \
        f32x2 pa_[16];                                                       \
        _Pragma("unroll")                                                    \
        for (int k = 0; k < 16; ++k) {                                       \
            pa_[k].x = SHFL(v2[k].x);                                        \
            pa_[k].y = SHFL(v2[k].y);                                        \
        }                                                                    \
        _Pragma("unroll")                                                    \
        for (int k = 0; k < 16; ++k)                                         \
            v2[k] = fma2(CV, v2[k], (SV) * pa_[k]);                          \
    }

// DPP lane gate (VALU pipe, short latency).
#define RY_DPP(PGETX, CV, SV)                                                \
    _Pragma("unroll")                                                        \
    for (int k = 0; k < 16; ++k) {                                           \
        f32x2 pa_;                                                           \
        pa_.x = PGETX(v2[k].x);                                              \
        pa_.y = PGETX(v2[k].y);                                              \
        v2[k] = fma2(CV, v2[k], (SV) * pa_);                                 \
    }

__global__ __launch_bounds__(256, 2) void qru_kernel(
    const float* __restrict__ x,   // [2048, 16]
    const float* __restrict__ w,   // [11]
    float* __restrict__ out)       // [2048, 11]
{
    const int lane = threadIdx.x & 63;
    const int n    = blockIdx.x * 4 + (threadIdx.x >> 6);

    // ---- inline-asm probe of permlane swap output order (executes on HW,
    //      cannot be constant-folded). Deterministic, wave-uniform. ----
    int mode = 0;  // 0 = shfl fallback
    {
        unsigned a32 = (unsigned)lane, b32 = 64u + (unsigned)lane;
        pswap32u(a32, b32);
        unsigned a16 = (unsigned)lane, b16 = 64u + (unsigned)lane;
        pswap16u(a16, b16);
        const unsigned d32a = (lane & 32) ? (unsigned)(lane + 32) : (unsigned)lane;
        const unsigned d32b = (lane & 32) ? (unsigned)(64 + lane) : (unsigned)(lane + 32);
        const unsigned d16a = (lane & 16) ? (unsigned)(48 + lane) : (unsigned)lane;
        const unsigned d16b = (lane & 16) ? (unsigned)(64 + lane) : (unsigned)(lane + 16);
        const bool dir32 = __all((a32 == d32a) && (b32 == d32b)) != 0;
        const bool rev32 = __all((a32 == d32b) && (b32 == d32a)) != 0;
        const bool dir16 = __all((a16 == d16a) && (b16 == d16b)) != 0;
        const bool rev16 = __all((a16 == d16b) && (b16 == d16a)) != 0;
        if ((dir32 || rev32) && (dir16 || rev16)) {
            const int m = 1 + (rev32 ? 1 : 0) + (rev16 ? 2 : 0);
            // m==1 (both direct) is exactly r12's config, empirically
            // falsified -> keep fallback. Only trust reversed combos.
            if (m != 1) mode = m;
        }
    }

    // ---- input angles (vectorized) + half-angle sin/cos ----
    const float4 xa = *(const float4*)(x + n * 16);
    const float4 xb = *(const float4*)(x + n * 16 + 4);
    const float4 xc = *(const float4*)(x + n * 16 + 8);
    const float xv[NQ] = {xa.x, xa.y, xa.z, xa.w, xb.x, xb.y, xb.z, xb.w,
                          xc.x, xc.y, xc.z};
    float ci[NQ], si[NQ];
#pragma unroll
    for (int q = 0; q < NQ; ++q) {
        const float h = xv[q] * 0.5f;
        si[q] = __sinf(h); ci[q] = __cosf(h);
    }
    float cw[NQ], sw[NQ];
#pragma unroll
    for (int q = 0; q < NQ; ++q) {
        const float h = w[q] * 0.5f;
        sw[q] = __sinf(h); cw[q] = __cosf(h);
    }

    // ---- initial product state ----
    const float laneF =
        ((lane & 32) ? si[5]  : ci[5])  *
        ((lane & 16) ? si[6]  : ci[6])  *
        ((lane & 8)  ? si[7]  : ci[7])  *
        ((lane & 4)  ? si[8]  : ci[8])  *
        ((lane & 2)  ? si[9]  : ci[9])  *
        ((lane & 1)  ? si[10] : ci[10]);

    f32x2 v2[16];
#pragma unroll
    for (int k = 0; k < 16; ++k) {
        const float base = laneF * ((k & 8) ? si[0] : ci[0])
                                 * ((k & 4) ? si[1] : ci[1])
                                 * ((k & 2) ? si[2] : ci[2])
                                 * ((k & 1) ? si[3] : ci[3]);
        v2[k].x = base * ci[4];
        v2[k].y = base * si[4];
    }

    // ---- folded per-lane coefficient constants (verified r3/r5/r6/r9) ----
    const float X0m = (lane & 1) ?  sw[0] : -sw[0];
    const float Y0m = (lane & 1) ? -cw[0] :  cw[0];
    // RY5 pair-frame (incoming CZ(4,5) = comp & lane-bit5; comp -> lane bit5
    // in swapped frame):  n0 = cw5*u0 + SS5*u1 ; n1 = sw5*u0 + C5m*u1
    const float SS5 = (lane & 32) ?  sw[5] : -sw[5];
    const float C5m = (lane & 32) ? -cw[5] :  cw[5];
    // RY6 pair-frame (incoming CZ(5,6): sigma by lane bit5, unchanged by swap)
    const float S6x = (lane & 32) ?  sw[6] : -sw[6];
    const float C6x = (lane & 32) ? -cw[6] :  cw[6];
    // Fallback partner-fetch-frame constants (r9):
    f32x2 Cv5; Cv5.x = cw[5]; Cv5.y = C5m;
    f32x2 Sv5; Sv5.x = SS5;   Sv5.y = sw[5];
    const f32x2 C6v  = b2(((lane & 48) == 48) ? -cw[6]  : cw[6]);
    const f32x2 S6v  = b2((lane & 48) ? sw[6]  : -sw[6]);
    // DPP gates (partner-fetch frame): own=(both)? -C:C ; cross=(either)? +S:-S
    const f32x2 C7v  = b2(((lane & 24) == 24) ? -cw[7]  : cw[7]);
    const f32x2 S7v  = b2((lane & 24) ? sw[7]  : -sw[7]);
    const f32x2 C8v  = b2(((lane & 12) == 12) ? -cw[8]  : cw[8]);
    const f32x2 S8v  = b2((lane & 12) ? sw[8]  : -sw[8]);
    const f32x2 C9v  = b2(((lane & 6)  == 6)  ? -cw[9]  : cw[9]);
    const f32x2 S9v  = b2((lane & 6)  ? sw[9]  : -sw[9]);
    const f32x2 C10v = b2(((lane & 3)  == 3)  ? -cw[10] : cw[10]);
    const f32x2 S10v = b2((lane & 3)  ? sw[10] : -sw[10]);

    // RY4 (comp butterfly), incoming CZ(3,4): sigma1 = -1 iff k odd.
    f32x2 C4p; C4p.x = cw[4];  C4p.y =  cw[4];
    f32x2 S4p; S4p.x = -sw[4]; S4p.y =  sw[4];
    f32x2 C4m; C4m.x = cw[4];  C4m.y = -cw[4];
    f32x2 S4m; S4m.x = sw[4];  S4m.y =  sw[4];

    auto shfl32 = [](float t) { return __shfl_xor(t, 32); };
    auto shfl16 = [](float t) { return __shfl_xor(t, 16); };
    auto dppx8  = [](float t) { return dpp_mov<DPP_XOR8>(t); };
    auto dppx4  = [](float t) { return dpp_mov<DPP_XOR3>(dpp_mov<DPP_XOR7>(t)); };
    auto dppx2  = [](float t) { return dpp_mov<DPP_XOR2>(t); };
    auto dppx1  = [](float t) { return dpp_mov<DPP_XOR1>(t); };

    auto run = [&](auto mc) {
        constexpr int  M   = decltype(mc)::value;
        constexpr bool PL  = (M >= 1);
        constexpr bool R32 = (M == 2 || M == 4);   // permlane32 outputs reversed
        constexpr bool R16 = (M == 3 || M == 4);   // permlane16 outputs reversed

        auto layer = [&](float X0, float Y0) {
            // RY0 on k bit 3 (incoming CZ folded into X0/Y0)
            {
                const f32x2 c0 = b2(cw[0]), s0 = b2(sw[0]);
                const f32x2 x0 = b2(X0),    y0 = b2(Y0);
#pragma unroll
                for (int k = 0; k < 8; ++k) {
                    const f32x2 a_ = v2[k], b_ = v2[k | 8];
                    v2[k]     = fma2(c0, a_, x0 * b_);
                    v2[k | 8] = fma2(s0, a_, y0 * b_);
                }
            }
            RY_K_F(2, 8, cw[1], sw[1])      // RY1, fold CZ(0,1)
            RY_K_F(1, 4, cw[2], sw[2])      // RY2, fold CZ(1,2)
            RY_K_F(0, 2, cw[3], sw[3])      // RY3, fold CZ(2,3)

            // RY4 (component), fold CZ(3,4) (k bit0)
#pragma unroll
            for (int k = 0; k < 16; ++k) {
                const f32x2 s_ = __builtin_shufflevector(v2[k], v2[k], 1, 0);
                v2[k] = (k & 1) ? fma2(C4m, v2[k], S4m * s_)
                                : fma2(C4p, v2[k], S4p * s_);
            }

            if constexpr (!PL) {
                RY_DS_B(shfl32, Cv5, Sv5)   // RY5, fold CZ(4,5)  — DS batched
                RY_DS_B(shfl16, C6v, S6v)   // RY6, fold CZ(5,6)  — DS batched
            } else {
                // RY5 (lane bit5): permlane32 pair trick, pure VALU
#pragma unroll
                for (int k = 0; k < 16; ++k) {
                    float d = v2[k].x, e = v2[k].y;
                    pswap32(d, e);
                    const float u0 = R32 ? e : d, u1 = R32 ? d : e;
                    float n0 = __builtin_fmaf(SS5, u1, cw[5] * u0);
                    float n1 = __builtin_fmaf(C5m, u1, sw[5] * u0);
                    pswap32(n0, n1);
                    v2[k].x = R32 ? n1 : n0;
                    v2[k].y = R32 ? n0 : n1;
                }
                // RY6 (lane bit4): permlane16 pair trick, pure VALU
#pragma unroll
                for (int k = 0; k < 16; ++k) {
                    float d = v2[k].x, e = v2[k].y;
                    pswap16(d, e);
                    const float u0 = R16 ? e : d, u1 = R16 ? d : e;
                    float n0 = __builtin_fmaf(S6x, u1, cw[6] * u0);
                    float n1 = __builtin_fmaf(C6x, u1, sw[6] * u0);
                    pswap16(n0, n1);
                    v2[k].x = R16 ? n1 : n0;
                    v2[k].y = R16 ? n0 : n1;
                }
            }

            RY_DPP(dppx8,  C7v,  S7v)       // RY7,  fold CZ(6,7)  — DPP
            RY_DPP(dppx4,  C8v,  S8v)       // RY8,  fold CZ(7,8)  — DPP x2
            RY_DPP(dppx2,  C9v,  S9v)       // RY9,  fold CZ(8,9)  — DPP
            RY_DPP(dppx1,  C10v, S10v)      // RY10, fold CZ(9,10) — DPP
            // CZ(10,0) -> folded into next layer's RY0; pure sign after last.
        };

        layer(-sw[0], cw[0]);               // layer 0: RY0 has no incoming CZ
#pragma unroll 1
        for (int l = 1; l < 6; ++l) layer(X0m, Y0m);
    };

    if (mode == 2)      run(IC<2>{});
    else if (mode == 3) run(IC<3>{});
    else if (mode == 4) run(IC<4>{});
    else                run(IC<0>{});

    // ---- measurement: out[w] = sum_i amp_i^2 * (1 - 2*bit_w(i)) ----
    f32x2 T = b2(0.f), A3 = b2(0.f), A2 = b2(0.f), A1 = b2(0.f), A0 = b2(0.f);
#pragma unroll
    for (int k = 0; k < 16; ++k) {
        const f32x2 p = v2[k] * v2[k];
        T = T + p;
        if (k & 8) A3 = A3 + p;
        if (k & 4) A2 = A2 + p;
        if (k & 2) A1 = A1 + p;
        if (k & 1) A0 = A0 + p;
    }
    const float tot = T.x + T.y;

    float q[NQ];
    q[0] = tot - 2.f * (A3.x + A3.y);
    q[1] = tot - 2.f * (A2.x + A2.y);
    q[2] = tot - 2.f * (A1.x + A1.y);
    q[3] = tot - 2.f * (A0.x + A0.y);
    q[4] = tot - 2.f * T.y;
    q[5]  = (lane & 32) ? -tot : tot;
    q[6]  = (lane & 16) ? -tot : tot;
    q[7]  = (lane & 8)  ? -tot : tot;
    q[8]  = (lane & 4)  ? -tot : tot;
    q[9]  = (lane & 2)  ? -tot : tot;
    q[10] = (lane & 1)  ? -tot : tot;

    // epilogue wave reduction (verified r9)
#pragma unroll
    for (int wq = 0; wq < NQ; ++wq) q[wq] += __shfl_xor(q[wq], 32);
#pragma unroll
    for (int wq = 0; wq < NQ; ++wq) q[wq] += __shfl_xor(q[wq], 16);
#pragma unroll
    for (int wq = 0; wq < NQ; ++wq) q[wq] += dpp_mov<DPP_XOR8>(q[wq]);
#pragma unroll
    for (int wq = 0; wq < NQ; ++wq)
        q[wq] += dpp_mov<DPP_XOR3>(dpp_mov<DPP_XOR7>(q[wq]));
#pragma unroll
    for (int wq = 0; wq < NQ; ++wq) q[wq] += dpp_mov<DPP_XOR2>(q[wq]);
#pragma unroll
    for (int wq = 0; wq < NQ; ++wq) q[wq] += dpp_mov<DPP_XOR1>(q[wq]);

    if (lane == 0) {
#pragma unroll
        for (int wq = 0; wq < NQ; ++wq) out[n * 11 + wq] = q[wq];
    }
}

extern "C" void kernel_launch(void* const* d_in, const int* in_sizes, int n_in,
                              void* d_out, int out_size, void* d_ws, size_t ws_size,
                              hipStream_t stream) {
    const float* x = (const float*)d_in[0];   // [8,256,16] f32
    const float* w = (const float*)d_in[1];   // [11] f32
    float* out = (float*)d_out;               // [8,256,11] f32

    qru_kernel<<<512, 256, 0, stream>>>(x, w, out);
}

// Round 14
// 25.640 us; speedup vs baseline: 1.1282x; 1.0028x over previous
//
#include <hip/hip_runtime.h>

#define NQ 11

// One wave per sample; 2048-amplitude real statevector in 16 float2 VGPR
// pairs per lane.  Amplitude index i (wire w <-> bit (10-w) of i):
//   i = (k<<7) | (comp<<6) | lane
//   wires 0..3  -> k bits 3..0    (packed float2 register butterflies)
//   wire  4     -> comp           (within-float2 butterfly)
//   wires 5..10 -> lane bits 5..0 (cross-lane butterflies)
// CZ gates folded into the NEXT RY's coefficients (verified r3/r5/r6/r9).
//
// Cross-lane mask 32/16: v_permlane{32,16}_swap_b32 inline asm. The swap's
// TRUE pair-permutation is classified at runtime among 4 involutory
// candidates (direct D, reversed R, cross C, cross-rev X) via exact lane
// tables; gate code is semantic-agnostic given 2 probed booleans:
//   U0_IN_D : which register holds the target-bit=0 amplitudes after swap
//   COMPB5  : whether comp maps to new lane-bit (true) or its complement
// Involution property guarantees: compute results in swapped frame, apply
// the same instruction again -> restored (v.x', v.y').
// r12 evidence (direct formulas -> bounded unitary-wrong error) says HW is
// NOT direct; both-direct classification maps to the verified shfl fallback.
// Masks 8,4,2,1 -> DPP (verified r5/r6/r9).

typedef float f32x2 __attribute__((ext_vector_type(2)));

template <int N> struct IC { static constexpr int value = N; };

__device__ __forceinline__ f32x2 b2(float s) { f32x2 r; r.x = s; r.y = s; return r; }
__device__ __forceinline__ f32x2 fma2(f32x2 a, f32x2 b, f32x2 c) {
    return __builtin_elementwise_fma(a, b, c);
}

__device__ __forceinline__ void pswap32(float& a, float& b) {
    asm volatile("v_permlane32_swap_b32 %0, %1" : "+v"(a), "+v"(b));
}
__device__ __forceinline__ void pswap16(float& a, float& b) {
    asm volatile("v_permlane16_swap_b32 %0, %1" : "+v"(a), "+v"(b));
}
__device__ __forceinline__ void pswap32u(unsigned& a, unsigned& b) {
    asm volatile("v_permlane32_swap_b32 %0, %1" : "+v"(a), "+v"(b));
}
__device__ __forceinline__ void pswap16u(unsigned& a, unsigned& b) {
    asm volatile("v_permlane16_swap_b32 %0, %1" : "+v"(a), "+v"(b));
}

template <int CTRL>
__device__ __forceinline__ float dpp_mov(float x) {
    const int xi = __builtin_bit_cast(int, x);
    return __builtin_bit_cast(float,
        __builtin_amdgcn_update_dpp(xi, xi, CTRL, 0xf, 0xf, false));
}
#define DPP_XOR1 0xB1   // quad_perm [1,0,3,2]
#define DPP_XOR2 0x4E   // quad_perm [2,3,0,1]
#define DPP_XOR3 0x1B   // quad_perm [3,2,1,0]
#define DPP_XOR7 0x141  // row_half_mirror
#define DPP_XOR8 0x128  // row_ror:8 (xor-8 within 16-lane row)

// Packed butterfly on k-bit KB; preceding CZ sign: -1 iff (k0 & KSB).
#define RY_K_F(KB, KSB, C, S)                                                \
    _Pragma("unroll")                                                        \
    for (int g = 0; g < 8; ++g) {                                            \
        const int k0 = ((g >> (KB)) << ((KB) + 1)) | (g & ((1 << (KB)) - 1));\
        const int k1 = k0 | (1 << (KB));                                     \
        const f32x2 a_ = v2[k0], b_ = v2[k1];                                \
        const f32x2 Cv = b2(C), Sv = b2(S);                                  \
        if (k0 & (KSB)) {                                                    \
            v2[k0] = fma2(Cv, a_, Sv * b_);                                  \
            v2[k1] = fma2(Sv, a_, -(Cv * b_));                               \
        } else {                                                             \
            v2[k0] = fma2(Cv, a_, -(Sv * b_));                               \
            v2[k1] = fma2(Sv, a_, Cv * b_);                                  \
        }                                                                    \
    }

// DS shuffle gate, BATCHED (verified r9 fallback path).
#define RY_DS_B(SHFL, CV, SV)                                                \
    {                                                                        \
        f32x2 pa_[16];                                                       \
        _Pragma("unroll")                                                    \
        for (int k = 0; k < 16; ++k) {                                       \
            pa_[k].x = SHFL(v2[k].x);                                        \
            pa_[k].y = SHFL(v2[k].y);                                        \
        }                                                                    \
        _Pragma("unroll")                                                    \
        for (int k = 0; k < 16; ++k)                                         \
            v2[k] = fma2(CV, v2[k], (SV) * pa_[k]);                          \
    }

// DPP lane gate (VALU pipe, short latency).
#define RY_DPP(PGETX, CV, SV)                                                \
    _Pragma("unroll")                                                        \
    for (int k = 0; k < 16; ++k) {                                           \
        f32x2 pa_;                                                           \
        pa_.x = PGETX(v2[k].x);                                              \
        pa_.y = PGETX(v2[k].y);                                              \
        v2[k] = fma2(CV, v2[k], (SV) * pa_);                                 \
    }

__global__ __launch_bounds__(256, 2) void qru_kernel(
    const float* __restrict__ x,   // [2048, 16]
    const float* __restrict__ w,   // [11]
    float* __restrict__ out)       // [2048, 11]
{
    const int lane = threadIdx.x & 63;
    const int n    = blockIdx.x * 4 + (threadIdx.x >> 6);
    const unsigned ul = (unsigned)lane;

    // ---- inline-asm probe: classify each swap among {D,R,C,X} ----
    int s32 = -1, s16 = -1;
    {
        unsigned a = ul, b = 64u + ul;
        pswap32u(a, b);
        const bool lo = !(lane & 32);
        if (__all(a == (lo ? ul : ul + 32u) && b == (lo ? ul + 32u : ul + 64u)))
            s32 = 0;  // D: a'={a_lo,b_lo} b'={a_hi,b_hi}
        else if (__all(a == (lo ? ul + 32u : ul + 64u) && b == (lo ? ul : ul + 32u)))
            s32 = 1;  // R
        else if (__all(a == (lo ? 96u + ul : ul) && b == (lo ? 64u + ul : ul - 32u)))
            s32 = 2;  // C: a'={b_hi,a_hi} b'={b_lo,a_lo}
        else if (__all(a == (lo ? 64u + ul : ul - 32u) && b == (lo ? 96u + ul : ul)))
            s32 = 3;  // X
    }
    {
        unsigned a = ul, b = 64u + ul;
        pswap16u(a, b);
        const bool lo16 = !(lane & 16);
        if (__all(a == (lo16 ? ul : 48u + ul) && b == (lo16 ? 16u + ul : 64u + ul)))
            s16 = 0;  // D: a'=[a0,b0,a2,b2] b'=[a1,b1,a3,b3]
        else if (__all(a == (lo16 ? 16u + ul : 64u + ul) && b == (lo16 ? ul : 48u + ul)))
            s16 = 1;  // R
        else if (__all(a == (lo16 ? 80u + ul : ul) && b == (lo16 ? 64u + ul : ul - 16u)))
            s16 = 2;  // C: a'=[b1,a1,b3,a3] b'=[b0,a0,b2,a2]
        else if (__all(a == (lo16 ? 64u + ul : ul - 16u) && b == (lo16 ? 80u + ul : ul)))
            s16 = 3;  // X
    }
    int mode = 0;
    bool compb5 = true;
    if (s32 >= 0 && s16 >= 0) {
        const bool u0d32 = (s32 == 0 || s32 == 3);
        const bool u0d16 = (s16 == 0 || s16 == 3);
        compb5 = (s32 == 0 || s32 == 1);   // comp == new lane-bit5?
        mode = 1 + (u0d32 ? 0 : 1) + (u0d16 ? 0 : 2);
        if (s32 == 0 && s16 == 0) mode = 0;  // both-direct: falsified by r12
    }

    // ---- input angles (vectorized) + half-angle sin/cos ----
    const float4 xa = *(const float4*)(x + n * 16);
    const float4 xb = *(const float4*)(x + n * 16 + 4);
    const float4 xc = *(const float4*)(x + n * 16 + 8);
    const float xv[NQ] = {xa.x, xa.y, xa.z, xa.w, xb.x, xb.y, xb.z, xb.w,
                          xc.x, xc.y, xc.z};
    float ci[NQ], si[NQ];
#pragma unroll
    for (int q = 0; q < NQ; ++q) {
        const float h = xv[q] * 0.5f;
        si[q] = __sinf(h); ci[q] = __cosf(h);
    }
    float cw[NQ], sw[NQ];
#pragma unroll
    for (int q = 0; q < NQ; ++q) {
        const float h = w[q] * 0.5f;
        sw[q] = __sinf(h); cw[q] = __cosf(h);
    }

    // ---- initial product state ----
    const float laneF =
        ((lane & 32) ? si[5]  : ci[5])  *
        ((lane & 16) ? si[6]  : ci[6])  *
        ((lane & 8)  ? si[7]  : ci[7])  *
        ((lane & 4)  ? si[8]  : ci[8])  *
        ((lane & 2)  ? si[9]  : ci[9])  *
        ((lane & 1)  ? si[10] : ci[10]);

    f32x2 v2[16];
#pragma unroll
    for (int k = 0; k < 16; ++k) {
        const float base = laneF * ((k & 8) ? si[0] : ci[0])
                                 * ((k & 4) ? si[1] : ci[1])
                                 * ((k & 2) ? si[2] : ci[2])
                                 * ((k & 1) ? si[3] : ci[3]);
        v2[k].x = base * ci[4];
        v2[k].y = base * si[4];
    }

    // ---- folded per-lane coefficient constants (verified r3/r5/r6/r9) ----
    const float X0m = (lane & 1) ?  sw[0] : -sw[0];
    const float Y0m = (lane & 1) ? -cw[0] :  cw[0];
    // RY5 swapped-frame u1-coefficients; comp1 here iff (bit5 == COMPB5):
    //   n0 = cw5*u0 + S5u1*u1 ; n1 = sw5*u0 + C5u1*u1
    const bool b5set = (lane & 32) != 0;
    const bool c1h   = (b5set == compb5);
    const float S5u1 = c1h ?  sw[5] : -sw[5];
    const float C5u1 = c1h ? -cw[5] :  cw[5];
    // RY6 swapped-frame u1-coefficients (sigma by amp's lane-bit5, preserved
    // by swap16; independent of comp encoding):
    const float S6u1 = b5set ?  sw[6] : -sw[6];
    const float C6u1 = b5set ? -cw[6] :  cw[6];
    // Fallback partner-fetch-frame constants (r9):
    const float SS5 = b5set ?  sw[5] : -sw[5];
    const float C5m = b5set ? -cw[5] :  cw[5];
    f32x2 Cv5; Cv5.x = cw[5]; Cv5.y = C5m;
    f32x2 Sv5; Sv5.x = SS5;   Sv5.y = sw[5];
    const f32x2 C6v  = b2(((lane & 48) == 48) ? -cw[6]  : cw[6]);
    const f32x2 S6v  = b2((lane & 48) ? sw[6]  : -sw[6]);
    // DPP gates (partner-fetch frame): own=(both)? -C:C ; cross=(either)? +S:-S
    const f32x2 C7v  = b2(((lane & 24) == 24) ? -cw[7]  : cw[7]);
    const f32x2 S7v  = b2((lane & 24) ? sw[7]  : -sw[7]);
    const f32x2 C8v  = b2(((lane & 12) == 12) ? -cw[8]  : cw[8]);
    const f32x2 S8v  = b2((lane & 12) ? sw[8]  : -sw[8]);
    const f32x2 C9v  = b2(((lane & 6)  == 6)  ? -cw[9]  : cw[9]);
    const f32x2 S9v  = b2((lane & 6)  ? sw[9]  : -sw[9]);
    const f32x2 C10v = b2(((lane & 3)  == 3)  ? -cw[10] : cw[10]);
    const f32x2 S10v = b2((lane & 3)  ? sw[10] : -sw[10]);

    // RY4 (comp butterfly), incoming CZ(3,4): sigma1 = -1 iff k odd.
    f32x2 C4p; C4p.x = cw[4];  C4p.y =  cw[4];
    f32x2 S4p; S4p.x = -sw[4]; S4p.y =  sw[4];
    f32x2 C4m; C4m.x = cw[4];  C4m.y = -cw[4];
    f32x2 S4m; S4m.x = sw[4];  S4m.y =  sw[4];

    auto shfl32 = [](float t) { return __shfl_xor(t, 32); };
    auto shfl16 = [](float t) { return __shfl_xor(t, 16); };
    auto dppx8  = [](float t) { return dpp_mov<DPP_XOR8>(t); };
    auto dppx4  = [](float t) { return dpp_mov<DPP_XOR3>(dpp_mov<DPP_XOR7>(t)); };
    auto dppx2  = [](float t) { return dpp_mov<DPP_XOR2>(t); };
    auto dppx1  = [](float t) { return dpp_mov<DPP_XOR1>(t); };

    auto run = [&](auto mc) {
        constexpr int  M    = decltype(mc)::value;
        constexpr bool PL   = (M >= 1);
        constexpr bool U0D32 = (M == 1 || M == 3);  // u0s land in first reg
        constexpr bool U0D16 = (M == 1 || M == 2);

        auto layer = [&](float X0, float Y0) {
            // RY0 on k bit 3 (incoming CZ folded into X0/Y0)
            {
                const f32x2 c0 = b2(cw[0]), s0 = b2(sw[0]);
                const f32x2 x0 = b2(X0),    y0 = b2(Y0);
#pragma unroll
                for (int k = 0; k < 8; ++k) {
                    const f32x2 a_ = v2[k], b_ = v2[k | 8];
                    v2[k]     = fma2(c0, a_, x0 * b_);
                    v2[k | 8] = fma2(s0, a_, y0 * b_);
                }
            }
            RY_K_F(2, 8, cw[1], sw[1])      // RY1, fold CZ(0,1)
            RY_K_F(1, 4, cw[2], sw[2])      // RY2, fold CZ(1,2)
            RY_K_F(0, 2, cw[3], sw[3])      // RY3, fold CZ(2,3)

            // RY4 (component), fold CZ(3,4) (k bit0)
#pragma unroll
            for (int k = 0; k < 16; ++k) {
                const f32x2 s_ = __builtin_shufflevector(v2[k], v2[k], 1, 0);
                v2[k] = (k & 1) ? fma2(C4m, v2[k], S4m * s_)
                                : fma2(C4p, v2[k], S4p * s_);
            }

            if constexpr (!PL) {
                RY_DS_B(shfl32, Cv5, Sv5)   // RY5, fold CZ(4,5)  — DS batched
                RY_DS_B(shfl16, C6v, S6v)   // RY6, fold CZ(5,6)  — DS batched
            } else {
                // RY5 (lane bit5): permlane32 pair trick, semantic-agnostic
#pragma unroll
                for (int k = 0; k < 16; ++k) {
                    float d = v2[k].x, e = v2[k].y;
                    pswap32(d, e);
                    const float u0 = U0D32 ? d : e;
                    const float u1 = U0D32 ? e : d;
                    const float n0 = __builtin_fmaf(S5u1, u1, cw[5] * u0);
                    const float n1 = __builtin_fmaf(C5u1, u1, sw[5] * u0);
                    float p = U0D32 ? n0 : n1;   // result for d-slot amps
                    float q = U0D32 ? n1 : n0;
                    pswap32(p, q);               // involution -> orig frame
                    v2[k].x = p; v2[k].y = q;
                }
                // RY6 (lane bit4): permlane16 pair trick, semantic-agnostic
#pragma unroll
                for (int k = 0; k < 16; ++k) {
                    float d = v2[k].x, e = v2[k].y;
                    pswap16(d, e);
                    const float u0 = U0D16 ? d : e;
                    const float u1 = U0D16 ? e : d;
                    const float n0 = __builtin_fmaf(S6u1, u1, cw[6] * u0);
                    const float n1 = __builtin_fmaf(C6u1, u1, sw[6] * u0);
                    float p = U0D16 ? n0 : n1;
                    float q = U0D16 ? n1 : n0;
                    pswap16(p, q);
                    v2[k].x = p; v2[k].y = q;
                }
            }

            RY_DPP(dppx8,  C7v,  S7v)       // RY7,  fold CZ(6,7)  — DPP
            RY_DPP(dppx4,  C8v,  S8v)       // RY8,  fold CZ(7,8)  — DPP x2
            RY_DPP(dppx2,  C9v,  S9v)       // RY9,  fold CZ(8,9)  — DPP
            RY_DPP(dppx1,  C10v, S10v)      // RY10, fold CZ(9,10) — DPP
            // CZ(10,0) -> folded into next layer's RY0; pure sign after last.
        };

        layer(-sw[0], cw[0]);               // layer 0: RY0 has no incoming CZ
#pragma unroll 1
        for (int l = 1; l < 6; ++l) layer(X0m, Y0m);
    };

    if (mode == 1)      run(IC<1>{});
    else if (mode == 2) run(IC<2>{});
    else if (mode == 3) run(IC<3>{});
    else if (mode == 4) run(IC<4>{});
    else                run(IC<0>{});

    // ---- measurement: out[w] = sum_i amp_i^2 * (1 - 2*bit_w(i)) ----
    f32x2 T = b2(0.f), A3 = b2(0.f), A2 = b2(0.f), A1 = b2(0.f), A0 = b2(0.f);
#pragma unroll
    for (int k = 0; k < 16; ++k) {
        const f32x2 p = v2[k] * v2[k];
        T = T + p;
        if (k & 8) A3 = A3 + p;
        if (k & 4) A2 = A2 + p;
        if (k & 2) A1 = A1 + p;
        if (k & 1) A0 = A0 + p;
    }
    const float tot = T.x + T.y;

    float q[NQ];
    q[0] = tot - 2.f * (A3.x + A3.y);
    q[1] = tot - 2.f * (A2.x + A2.y);
    q[2] = tot - 2.f * (A1.x + A1.y);
    q[3] = tot - 2.f * (A0.x + A0.y);
    q[4] = tot - 2.f * T.y;
    q[5]  = (lane & 32) ? -tot : tot;
    q[6]  = (lane & 16) ? -tot : tot;
    q[7]  = (lane & 8)  ? -tot : tot;
    q[8]  = (lane & 4)  ? -tot : tot;
    q[9]  = (lane & 2)  ? -tot : tot;
    q[10] = (lane & 1)  ? -tot : tot;

    // epilogue wave reduction (verified r9)
#pragma unroll
    for (int wq = 0; wq < NQ; ++wq) q[wq] += __shfl_xor(q[wq], 32);
#pragma unroll
    for (int wq = 0; wq < NQ; ++wq) q[wq] += __shfl_xor(q[wq], 16);
#pragma unroll
    for (int wq = 0; wq < NQ; ++wq) q[wq] += dpp_mov<DPP_XOR8>(q[wq]);
#pragma unroll
    for (int wq = 0; wq < NQ; ++wq)
        q[wq] += dpp_mov<DPP_XOR3>(dpp_mov<DPP_XOR7>(q[wq]));
#pragma unroll
    for (int wq = 0; wq < NQ; ++wq) q[wq] += dpp_mov<DPP_XOR2>(q[wq]);
#pragma unroll
    for (int wq = 0; wq < NQ; ++wq) q[wq] += dpp_mov<DPP_XOR1>(q[wq]);

    if (lane == 0) {
#pragma unroll
        for (int wq = 0; wq < NQ; ++wq) out[n * 11 + wq] = q[wq];
    }
}

extern "C" void kernel_launch(void* const* d_in, const int* in_sizes, int n_in,
                              void* d_out, int out_size, void* d_ws, size_t ws_size,
                              hipStream_t stream) {
    const float* x = (const float*)d_in[0];   // [8,256,16] f32
    const float* w = (const float*)d_in[1];   // [11] f32
    float* out = (float*)d_out;               // [8,256,11] f32

    qru_kernel<<<512, 256, 0, stream>>>(x, w, out);
}

// Round 15
// 25.339 us; speedup vs baseline: 1.1416x; 1.0119x over previous
//
#include <hip/hip_runtime.h>

#define NQ 11

// One wave per sample; 2048-amplitude real statevector in 16 float2 VGPR
// pairs per lane.  Amplitude index i (wire w <-> bit (10-w) of i):
//   i = (k<<7) | (comp<<6) | lane
//   wires 0..3  -> k bits 3..0    (packed float2 register butterflies)
//   wire  4     -> comp           (within-float2 butterfly)
//   wires 5..10 -> lane bits 5..0 (cross-lane butterflies)
// CZ gates folded into the NEXT RY's coefficients (verified r3/r5/r6/r9).
//
// Cross-lane mask 32/16: v_permlane{32,16}_swap_b32 inline asm under the
// FX (full-xor exchange) hypothesis:  a'[l] = b[l^M], b'[l] = a[l^M].
// Evidence: r12 (direct-assumption formulas -> bounded unitary-wrong error,
// i.e. SOME permutation, not direct); r13/r14 probes excluded direct,
// reversed, cross, cross-reversed. FX is the remaining natural involution
// and matches HK's "one swap fills two output words" usage.
// Under FX, ONE swap of (v.x, v.y) yields BOTH components' butterfly
// partners (px'=y[l^M], py'=x[l^M]) -> the gate uses the byte-identical
// r9-verified partner-fetch constants; no swapped-frame algebra at all.
// Probe checks the exact FX lane map per instruction; mismatch -> verified
// r9 shfl fallback (zero regression risk).
// Masks 8,4,2,1 -> DPP (verified r5/r6/r9).

typedef float f32x2 __attribute__((ext_vector_type(2)));

template <int N> struct IC { static constexpr int value = N; };

__device__ __forceinline__ f32x2 b2(float s) { f32x2 r; r.x = s; r.y = s; return r; }
__device__ __forceinline__ f32x2 fma2(f32x2 a, f32x2 b, f32x2 c) {
    return __builtin_elementwise_fma(a, b, c);
}

__device__ __forceinline__ void pswap32(float& a, float& b) {
    asm volatile("v_permlane32_swap_b32 %0, %1" : "+v"(a), "+v"(b));
}
__device__ __forceinline__ void pswap16(float& a, float& b) {
    asm volatile("v_permlane16_swap_b32 %0, %1" : "+v"(a), "+v"(b));
}
__device__ __forceinline__ void pswap32u(unsigned& a, unsigned& b) {
    asm volatile("v_permlane32_swap_b32 %0, %1" : "+v"(a), "+v"(b));
}
__device__ __forceinline__ void pswap16u(unsigned& a, unsigned& b) {
    asm volatile("v_permlane16_swap_b32 %0, %1" : "+v"(a), "+v"(b));
}

template <int CTRL>
__device__ __forceinline__ float dpp_mov(float x) {
    const int xi = __builtin_bit_cast(int, x);
    return __builtin_bit_cast(float,
        __builtin_amdgcn_update_dpp(xi, xi, CTRL, 0xf, 0xf, false));
}
#define DPP_XOR1 0xB1   // quad_perm [1,0,3,2]
#define DPP_XOR2 0x4E   // quad_perm [2,3,0,1]
#define DPP_XOR3 0x1B   // quad_perm [3,2,1,0]
#define DPP_XOR7 0x141  // row_half_mirror
#define DPP_XOR8 0x128  // row_ror:8 (xor-8 within 16-lane row)

// Packed butterfly on k-bit KB; preceding CZ sign: -1 iff (k0 & KSB).
#define RY_K_F(KB, KSB, C, S)                                                \
    _Pragma("unroll")                                                        \
    for (int g = 0; g < 8; ++g) {                                            \
        const int k0 = ((g >> (KB)) << ((KB) + 1)) | (g & ((1 << (KB)) - 1));\
        const int k1 = k0 | (1 << (KB));                                     \
        const f32x2 a_ = v2[k0], b_ = v2[k1];                                \
        const f32x2 Cv = b2(C), Sv = b2(S);                                  \
        if (k0 & (KSB)) {                                                    \
            v2[k0] = fma2(Cv, a_, Sv * b_);                                  \
            v2[k1] = fma2(Sv, a_, -(Cv * b_));                               \
        } else {                                                             \
            v2[k0] = fma2(Cv, a_, -(Sv * b_));                               \
            v2[k1] = fma2(Sv, a_, Cv * b_);                                  \
        }                                                                    \
    }

// DS shuffle gate, BATCHED (verified r9 fallback path).
#define RY_DS_B(SHFL, CV, SV)                                                \
    {                                                                        \
        f32x2 pa_[16];                                                       \
        _Pragma("unroll")                                                    \
        for (int k = 0; k < 16; ++k) {                                       \
            pa_[k].x = SHFL(v2[k].x);                                        \
            pa_[k].y = SHFL(v2[k].y);                                        \
        }                                                                    \
        _Pragma("unroll")                                                    \
        for (int k = 0; k < 16; ++k)                                         \
            v2[k] = fma2(CV, v2[k], (SV) * pa_[k]);                          \
    }

// DPP lane gate (VALU pipe, short latency).
#define RY_DPP(PGETX, CV, SV)                                                \
    _Pragma("unroll")                                                        \
    for (int k = 0; k < 16; ++k) {                                           \
        f32x2 pa_;                                                           \
        pa_.x = PGETX(v2[k].x);                                              \
        pa_.y = PGETX(v2[k].y);                                              \
        v2[k] = fma2(CV, v2[k], (SV) * pa_);                                 \
    }

__global__ __launch_bounds__(256, 2) void qru_kernel(
    const float* __restrict__ x,   // [2048, 16]
    const float* __restrict__ w,   // [11]
    float* __restrict__ out)       // [2048, 11]
{
    const int lane = threadIdx.x & 63;
    const int n    = blockIdx.x * 4 + (threadIdx.x >> 6);
    const unsigned ul = (unsigned)lane;

    // ---- inline-asm probe: does each swap implement FX (a'[l]=b[l^M],
    //      b'[l]=a[l^M])?  Executes on HW; cannot be constant-folded. ----
    int fxmask = 0;
    {
        unsigned a = ul, b = 64u + ul;
        pswap32u(a, b);
        const bool lo = !(lane & 32);
        // FX32: a' = lo ? b[l+32]=96+l : b[l-32]=l+32 ; b' = lo ? l+32 : l-32
        if (__all((a == (lo ? 96u + ul : ul + 32u)) &&
                  (b == (lo ? ul + 32u : ul - 32u))))
            fxmask |= 1;
    }
    {
        unsigned a = ul, b = 64u + ul;
        pswap16u(a, b);
        const bool lo16 = !(lane & 16);
        // FX16: a' = lo16 ? b[l+16]=80+l : b[l-16]=48+l ; b' = lo16 ? l+16 : l-16
        if (__all((a == (lo16 ? 80u + ul : 48u + ul)) &&
                  (b == (lo16 ? ul + 16u : ul - 16u))))
            fxmask |= 2;
    }

    // ---- input angles (vectorized) + half-angle sin/cos ----
    const float4 xa = *(const float4*)(x + n * 16);
    const float4 xb = *(const float4*)(x + n * 16 + 4);
    const float4 xc = *(const float4*)(x + n * 16 + 8);
    const float xv[NQ] = {xa.x, xa.y, xa.z, xa.w, xb.x, xb.y, xb.z, xb.w,
                          xc.x, xc.y, xc.z};
    float ci[NQ], si[NQ];
#pragma unroll
    for (int q = 0; q < NQ; ++q) {
        const float h = xv[q] * 0.5f;
        si[q] = __sinf(h); ci[q] = __cosf(h);
    }
    float cw[NQ], sw[NQ];
#pragma unroll
    for (int q = 0; q < NQ; ++q) {
        const float h = w[q] * 0.5f;
        sw[q] = __sinf(h); cw[q] = __cosf(h);
    }

    // ---- initial product state ----
    const float laneF =
        ((lane & 32) ? si[5]  : ci[5])  *
        ((lane & 16) ? si[6]  : ci[6])  *
        ((lane & 8)  ? si[7]  : ci[7])  *
        ((lane & 4)  ? si[8]  : ci[8])  *
        ((lane & 2)  ? si[9]  : ci[9])  *
        ((lane & 1)  ? si[10] : ci[10]);

    f32x2 v2[16];
#pragma unroll
    for (int k = 0; k < 16; ++k) {
        const float base = laneF * ((k & 8) ? si[0] : ci[0])
                                 * ((k & 4) ? si[1] : ci[1])
                                 * ((k & 2) ? si[2] : ci[2])
                                 * ((k & 1) ? si[3] : ci[3]);
        v2[k].x = base * ci[4];
        v2[k].y = base * si[4];
    }

    // ---- folded per-lane coefficient constants (verified r3/r5/r6/r9) ----
    const float X0m = (lane & 1) ?  sw[0] : -sw[0];
    const float Y0m = (lane & 1) ? -cw[0] :  cw[0];
    // RY5 partner-fetch frame (incoming CZ(4,5) = comp & lane-bit5):
    //   comp0: v.x' = cw5*v.x + SS5*partner_x ; comp1: v.y' = C5m*v.y + sw5*partner_y
    const float SS5 = (lane & 32) ?  sw[5] : -sw[5];
    const float C5m = (lane & 32) ? -cw[5] :  cw[5];
    f32x2 Cv5; Cv5.x = cw[5]; Cv5.y = C5m;
    f32x2 Sv5; Sv5.x = SS5;   Sv5.y = sw[5];
    // RY6 partner-fetch frame (incoming CZ(5,6) = lane bits 5&4):
    const f32x2 C6v  = b2(((lane & 48) == 48) ? -cw[6]  : cw[6]);
    const f32x2 S6v  = b2((lane & 48) ? sw[6]  : -sw[6]);
    // DPP gates: own=(both)? -C:C ; cross=(either)? +S:-S
    const f32x2 C7v  = b2(((lane & 24) == 24) ? -cw[7]  : cw[7]);
    const f32x2 S7v  = b2((lane & 24) ? sw[7]  : -sw[7]);
    const f32x2 C8v  = b2(((lane & 12) == 12) ? -cw[8]  : cw[8]);
    const f32x2 S8v  = b2((lane & 12) ? sw[8]  : -sw[8]);
    const f32x2 C9v  = b2(((lane & 6)  == 6)  ? -cw[9]  : cw[9]);
    const f32x2 S9v  = b2((lane & 6)  ? sw[9]  : -sw[9]);
    const f32x2 C10v = b2(((lane & 3)  == 3)  ? -cw[10] : cw[10]);
    const f32x2 S10v = b2((lane & 3)  ? sw[10] : -sw[10]);

    // RY4 (comp butterfly), incoming CZ(3,4): sigma1 = -1 iff k odd.
    f32x2 C4p; C4p.x = cw[4];  C4p.y =  cw[4];
    f32x2 S4p; S4p.x = -sw[4]; S4p.y =  sw[4];
    f32x2 C4m; C4m.x = cw[4];  C4m.y = -cw[4];
    f32x2 S4m; S4m.x = sw[4];  S4m.y =  sw[4];

    auto shfl32 = [](float t) { return __shfl_xor(t, 32); };
    auto shfl16 = [](float t) { return __shfl_xor(t, 16); };
    auto dppx8  = [](float t) { return dpp_mov<DPP_XOR8>(t); };
    auto dppx4  = [](float t) { return dpp_mov<DPP_XOR3>(dpp_mov<DPP_XOR7>(t)); };
    auto dppx2  = [](float t) { return dpp_mov<DPP_XOR2>(t); };
    auto dppx1  = [](float t) { return dpp_mov<DPP_XOR1>(t); };

    auto run = [&](auto mc) {
        constexpr int  M    = decltype(mc)::value;
        constexpr bool FX32 = (M & 1) != 0;
        constexpr bool FX16 = (M & 2) != 0;

        auto layer = [&](float X0, float Y0) {
            // RY0 on k bit 3 (incoming CZ folded into X0/Y0)
            {
                const f32x2 c0 = b2(cw[0]), s0 = b2(sw[0]);
                const f32x2 x0 = b2(X0),    y0 = b2(Y0);
#pragma unroll
                for (int k = 0; k < 8; ++k) {
                    const f32x2 a_ = v2[k], b_ = v2[k | 8];
                    v2[k]     = fma2(c0, a_, x0 * b_);
                    v2[k | 8] = fma2(s0, a_, y0 * b_);
                }
            }
            RY_K_F(2, 8, cw[1], sw[1])      // RY1, fold CZ(0,1)
            RY_K_F(1, 4, cw[2], sw[2])      // RY2, fold CZ(1,2)
            RY_K_F(0, 2, cw[3], sw[3])      // RY3, fold CZ(2,3)

            // RY4 (component), fold CZ(3,4) (k bit0)
#pragma unroll
            for (int k = 0; k < 16; ++k) {
                const f32x2 s_ = __builtin_shufflevector(v2[k], v2[k], 1, 0);
                v2[k] = (k & 1) ? fma2(C4m, v2[k], S4m * s_)
                                : fma2(C4p, v2[k], S4p * s_);
            }

            // RY5 (lane bit5), fold CZ(4,5)
            if constexpr (FX32) {
                // FX: one swap yields BOTH partners: px'=y[l^32], py'=x[l^32]
#pragma unroll
                for (int k = 0; k < 16; ++k) {
                    float px = v2[k].x, py = v2[k].y;
                    pswap32(px, py);
                    v2[k].x = __builtin_fmaf(Sv5.x, py, Cv5.x * v2[k].x);
                    v2[k].y = __builtin_fmaf(Sv5.y, px, Cv5.y * v2[k].y);
                }
            } else {
                RY_DS_B(shfl32, Cv5, Sv5)
            }

            // RY6 (lane bit4), fold CZ(5,6)
            if constexpr (FX16) {
#pragma unroll
                for (int k = 0; k < 16; ++k) {
                    float px = v2[k].x, py = v2[k].y;
                    pswap16(px, py);    // px'=y[l^16], py'=x[l^16]
                    v2[k].x = __builtin_fmaf(S6v.x, py, C6v.x * v2[k].x);
                    v2[k].y = __builtin_fmaf(S6v.y, px, C6v.y * v2[k].y);
                }
            } else {
                RY_DS_B(shfl16, C6v, S6v)
            }

            RY_DPP(dppx8,  C7v,  S7v)       // RY7,  fold CZ(6,7)  — DPP
            RY_DPP(dppx4,  C8v,  S8v)       // RY8,  fold CZ(7,8)  — DPP x2
            RY_DPP(dppx2,  C9v,  S9v)       // RY9,  fold CZ(8,9)  — DPP
            RY_DPP(dppx1,  C10v, S10v)      // RY10, fold CZ(9,10) — DPP
            // CZ(10,0) -> folded into next layer's RY0; pure sign after last.
        };

        layer(-sw[0], cw[0]);               // layer 0: RY0 has no incoming CZ
#pragma unroll 1
        for (int l = 1; l < 6; ++l) layer(X0m, Y0m);
    };

    if (fxmask == 3)      run(IC<3>{});
    else if (fxmask == 1) run(IC<1>{});
    else if (fxmask == 2) run(IC<2>{});
    else                  run(IC<0>{});

    // ---- measurement: out[w] = sum_i amp_i^2 * (1 - 2*bit_w(i)) ----
    f32x2 T = b2(0.f), A3 = b2(0.f), A2 = b2(0.f), A1 = b2(0.f), A0 = b2(0.f);
#pragma unroll
    for (int k = 0; k < 16; ++k) {
        const f32x2 p = v2[k] * v2[k];
        T = T + p;
        if (k & 8) A3 = A3 + p;
        if (k & 4) A2 = A2 + p;
        if (k & 2) A1 = A1 + p;
        if (k & 1) A0 = A0 + p;
    }
    const float tot = T.x + T.y;

    float q[NQ];
    q[0] = tot - 2.f * (A3.x + A3.y);
    q[1] = tot - 2.f * (A2.x + A2.y);
    q[2] = tot - 2.f * (A1.x + A1.y);
    q[3] = tot - 2.f * (A0.x + A0.y);
    q[4] = tot - 2.f * T.y;
    q[5]  = (lane & 32) ? -tot : tot;
    q[6]  = (lane & 16) ? -tot : tot;
    q[7]  = (lane & 8)  ? -tot : tot;
    q[8]  = (lane & 4)  ? -tot : tot;
    q[9]  = (lane & 2)  ? -tot : tot;
    q[10] = (lane & 1)  ? -tot : tot;

    // epilogue wave reduction (verified r9)
#pragma unroll
    for (int wq = 0; wq < NQ; ++wq) q[wq] += __shfl_xor(q[wq], 32);
#pragma unroll
    for (int wq = 0; wq < NQ; ++wq) q[wq] += __shfl_xor(q[wq], 16);
#pragma unroll
    for (int wq = 0; wq < NQ; ++wq) q[wq] += dpp_mov<DPP_XOR8>(q[wq]);
#pragma unroll
    for (int wq = 0; wq < NQ; ++wq)
        q[wq] += dpp_mov<DPP_XOR3>(dpp_mov<DPP_XOR7>(q[wq]));
#pragma unroll
    for (int wq = 0; wq < NQ; ++wq) q[wq] += dpp_mov<DPP_XOR2>(q[wq]);
#pragma unroll
    for (int wq = 0; wq < NQ; ++wq) q[wq] += dpp_mov<DPP_XOR1>(q[wq]);

    if (lane == 0) {
#pragma unroll
        for (int wq = 0; wq < NQ; ++wq) out[n * 11 + wq] = q[wq];
    }
}

extern "C" void kernel_launch(void* const* d_in, const int* in_sizes, int n_in,
                              void* d_out, int out_size, void* d_ws, size_t ws_size,
                              hipStream_t stream) {
    const float* x = (const float*)d_in[0];   // [8,256,16] f32
    const float* w = (const float*)d_in[1];   // [11] f32
    float* out = (float*)d_out;               // [8,256,11] f32

    qru_kernel<<<512, 256, 0, stream>>>(x, w, out);
}